// Round 16
// baseline (337.560 us; speedup 1.0000x reference)
//
#include <hip/hip_runtime.h>

// Problem constants (from reference)
#define NN 50000
#define NE 800000
#define HH 64
#define LL 4
#define GG 500
#define CC 10
#define BN_EPS 1e-5f
#define SCB 200     // scan blocks (200*256 = 51200 >= 50000)
#define NPART 6250  // NN/8 dst nodes per XCD partition
#define ECHUNK 2048 // edges per chunk in partitioned hist/scatter
#define NCHUNK 391  // ceil(NE/ECHUNK)
#define CASTB 3125  // k_prep: cast blocks
#define AGGB2 782   // ceil(NN/64) blocks per aggregation pass

typedef short bf16x8 __attribute__((ext_vector_type(8)));
typedef float f32x4  __attribute__((ext_vector_type(4)));
typedef unsigned int u32x4 __attribute__((ext_vector_type(4)));   // for nontemporal store

// ---- bf16 helpers (storage-only precision cut; math stays fp32) ----
__device__ inline float bf2f(unsigned int u16) {
    union { unsigned int i; float f; } v; v.i = u16 << 16; return v.f;
}
__device__ inline unsigned short f2bf(float f) {
    union { float f; unsigned int i; } v; v.f = f;
    unsigned int u = v.i + 0x7fffu + ((v.i >> 16) & 1u);   // round-nearest-even
    return (unsigned short)(u >> 16);
}
__device__ inline void addrow8(float* acc, uint4 u) {
    #pragma unroll
    for (int q = 0; q < 4; ++q) {
        unsigned int w = (&u.x)[q];
        union { unsigned int i; float f; } lo, hi;
        lo.i = w << 16; hi.i = w & 0xffff0000u;
        acc[2 * q]     += lo.f;
        acc[2 * q + 1] += hi.f;
    }
}

// ---------------------------------------------------------------------------
// Fused prep: blocks [0,3125) cast x -> SPLIT bf16 layout hb[2][NN][32];
// blocks [3125,3253) pack split-bf16 weight fragments (MFMA B-layout).
// ---------------------------------------------------------------------------
__global__ __launch_bounds__(256) void k_prep(const float* __restrict__ x, unsigned short* __restrict__ xb,
                                              const float* __restrict__ cW1, const float* __restrict__ cW2,
                                              unsigned short* __restrict__ fragW)
{
    if (blockIdx.x < CASTB) {
        int i = blockIdx.x * 256 + threadIdx.x;   // float4 groups, NN*16 total
        if (i < NN * 16) {
            float4 v = ((const float4*)x)[i];
            uint2 p;
            p.x = (unsigned int)f2bf(v.x) | ((unsigned int)f2bf(v.y) << 16);
            p.y = (unsigned int)f2bf(v.z) | ((unsigned int)f2bf(v.w) << 16);
            int n = i >> 4, cq = i & 15;
            int half = cq >> 3, c8 = cq & 7;
            ((uint2*)xb)[((size_t)half * NN + n) * 8 + c8] = p;
        }
        return;
    }
    int idx = (blockIdx.x - CASTB) * 256 + threadIdx.x;   // 32768 total
    if (idx >= LL * 2 * 4 * 2 * 64 * 8) return;
    int j    = idx & 7;
    int lane = (idx >> 3) & 63;
    int kh   = (idx >> 9) & 1;
    int ct   = (idx >> 10) & 3;
    int g    = (idx >> 12) & 1;
    int L    = idx >> 13;
    int k = kh * 32 + (lane >> 4) * 8 + j;
    int n = ct * 16 + (lane & 15);
    const float* W = (g == 0 ? cW1 : cW2) + (size_t)L * HH * HH;
    float w = W[k * HH + n];
    unsigned short hi = f2bf(w);
    unsigned short lo = f2bf(w - bf2f(hi));
    size_t fhi = ((size_t)L * 32 + ((g * 2 + 0) * 4 + ct) * 2 + kh) * 512 + lane * 8 + j;
    size_t flo = ((size_t)L * 32 + ((g * 2 + 1) * 4 + ct) * 2 + kh) * 512 + lane * 8 + j;
    fragW[fhi] = hi;
    fragW[flo] = lo;
}

// ---------------------------------------------------------------------------
// CSR build, XCD-partitioned (R10: kills cross-XCD dirty-line ping-pong).
// ---------------------------------------------------------------------------
__global__ __launch_bounds__(256) void k_hist8(const int* __restrict__ dst, int* __restrict__ deg) {
    int part  = blockIdx.x & 7;
    int chunk = blockIdx.x >> 3;
    int lo = part * NPART, hi = lo + NPART;
    int base = chunk * ECHUNK + threadIdx.x;
    #pragma unroll
    for (int i = 0; i < 8; ++i) {
        int e = base + i * 256;
        if (e < NE) {
            int d = dst[e];
            if (d >= lo && d < hi) atomicAdd(&deg[d], 1);
        }
    }
}

__global__ __launch_bounds__(256) void k_scan1(const int* __restrict__ deg, int* __restrict__ incl,
                                               int* __restrict__ bsum) {
    int t = threadIdx.x;
    int idx = blockIdx.x * 256 + t;
    __shared__ int s[256];
    int v = (idx < NN) ? deg[idx] : 0;
    s[t] = v;
    __syncthreads();
    for (int off = 1; off < 256; off <<= 1) {
        int u = (t >= off) ? s[t - off] : 0;
        __syncthreads();
        if (t >= off) s[t] += u;
        __syncthreads();
    }
    if (idx < NN) incl[idx] = s[t];
    if (t == 255) bsum[blockIdx.x] = s[255];
}

__global__ __launch_bounds__(256) void k_scan3f(const int* __restrict__ deg, const int* __restrict__ incl,
                                                const int* __restrict__ bsum, int* __restrict__ row_ptr) {
    int t = threadIdx.x;
    __shared__ int s[256];
    int v = (t < SCB) ? bsum[t] : 0;
    s[t] = v;
    __syncthreads();
    for (int off = 1; off < 256; off <<= 1) {
        int u = (t >= off) ? s[t - off] : 0;
        __syncthreads();
        if (t >= off) s[t] += u;
        __syncthreads();
    }
    int boff_b = (blockIdx.x == 0) ? 0 : s[blockIdx.x - 1];
    if (blockIdx.x == 0 && t == 0) row_ptr[NN] = s[SCB - 1];
    int idx = blockIdx.x * 256 + t;
    if (idx < NN) row_ptr[idx] = incl[idx] - deg[idx] + boff_b;
}

__global__ __launch_bounds__(256) void k_scatter8(const int* __restrict__ src, const int* __restrict__ dst,
                                                  const int* __restrict__ row_ptr, int* __restrict__ cursor,
                                                  int* __restrict__ col) {
    int part  = blockIdx.x & 7;
    int chunk = blockIdx.x >> 3;
    int lo = part * NPART, hi = lo + NPART;
    int base = chunk * ECHUNK + threadIdx.x;
    #pragma unroll
    for (int i = 0; i < 8; ++i) {
        int e = base + i * 256;
        if (e < NE) {
            int d = dst[e];
            if (d >= lo && d < hi) {
                int pos = atomicAdd(&cursor[d], 1);
                col[row_ptr[d] + pos] = src[e];
            }
        }
    }
}

// ---------------------------------------------------------------------------
// Aggregation, feature-split two-pass: pass p gathers half p of the h table
// (hb[p][NN][32], 3.2 MB < 4 MB per-XCD L2 -> resident after warmup).
// 4-lane group per node-half (one 64B line per gather), 16 nodes/wave.
// aggb writes nontemporal so streaming output doesn't evict the table.
// ---------------------------------------------------------------------------
__global__ __launch_bounds__(256) void k_agg2(
    const unsigned short* __restrict__ hb, unsigned short* __restrict__ aggb,
    const int* __restrict__ row_ptr, const int* __restrict__ col)
{
    int tid  = threadIdx.x;
    int lane = tid & 63;
    int wave = tid >> 6;
    int gl   = lane & 3;    // lane in 4-group: features gl*8..gl*8+7 of the half
    int grp  = lane >> 2;   // 16 node slots per wave
    int bid  = blockIdx.x;
    int pass = 0;
    if (bid >= AGGB2) { pass = 1; bid -= AGGB2; }
    int n = bid * 64 + wave * 16 + grp;
    if (n >= NN) return;

    const uint4* hv = (const uint4*)(hb + (size_t)pass * NN * 32);  // 4 uint4/row-half
    float acc[8]  = {0.f, 0.f, 0.f, 0.f, 0.f, 0.f, 0.f, 0.f};
    float acc2[8] = {0.f, 0.f, 0.f, 0.f, 0.f, 0.f, 0.f, 0.f};
    addrow8(acc, hv[(size_t)n * 4 + gl]);

    int j = row_ptr[n], fin = row_ptr[n + 1];
    for (; j + 4 <= fin; j += 4) {
        int s0 = col[j], s1 = col[j + 1], s2 = col[j + 2], s3 = col[j + 3];
        uint4 u0 = hv[(size_t)s0 * 4 + gl];
        uint4 u1 = hv[(size_t)s1 * 4 + gl];
        uint4 u2 = hv[(size_t)s2 * 4 + gl];
        uint4 u3 = hv[(size_t)s3 * 4 + gl];
        addrow8(acc, u0);  addrow8(acc2, u1);
        addrow8(acc, u2);  addrow8(acc2, u3);
    }
    for (; j < fin; ++j)
        addrow8(acc, hv[(size_t)col[j] * 4 + gl]);

    #pragma unroll
    for (int q = 0; q < 8; ++q) acc[q] += acc2[q];

    u32x4 o;
    o.x = (unsigned int)f2bf(acc[0]) | ((unsigned int)f2bf(acc[1]) << 16);
    o.y = (unsigned int)f2bf(acc[2]) | ((unsigned int)f2bf(acc[3]) << 16);
    o.z = (unsigned int)f2bf(acc[4]) | ((unsigned int)f2bf(acc[5]) << 16);
    o.w = (unsigned int)f2bf(acc[6]) | ((unsigned int)f2bf(acc[7]) << 16);
    // aggb stays interleaved [n][64]; chunk index = pass*4+gl covers cols (pass*32+gl*8..+8)
    __builtin_nontemporal_store(o, (u32x4*)(aggb + (size_t)n * HH) + (pass * 4 + gl));
}

// ---------------------------------------------------------------------------
// MFMA MLP layer + fused pooling (verified R12, absmax 1.0).
// h_out written in SPLIT layout [2][NN][32] for next layer's gather.
// ---------------------------------------------------------------------------
#define MT 128
#define SAB 80    // bf16 tile row stride in shorts (160B, 16B-aligned)
#define SOF 68    // fp32 out tile row stride in floats

__global__ __launch_bounds__(256) void k_mlp2(
    const unsigned short* __restrict__ agg, unsigned short* __restrict__ h_out,
    const int* __restrict__ batch, float* __restrict__ pooled, int layer,
    const unsigned short* __restrict__ fragW,
    const float* __restrict__ lb1, const float* __restrict__ g1,
    const float* __restrict__ bb1, const float* __restrict__ m1, const float* __restrict__ v1,
    const float* __restrict__ lb2, const float* __restrict__ g2,
    const float* __restrict__ bb2, const float* __restrict__ m2, const float* __restrict__ v2)
{
    __shared__ unsigned short sHi[128 * SAB];   // agg tile, then z1hi
    __shared__ unsigned short sLo[128 * SAB];   // z1lo
    __shared__ float sOut[128 * SOF];           // z2 fp32 (pooling + copy-out)
    __shared__ float red[256];

    int tid  = threadIdx.x;
    int lane = tid & 63;
    int wave = tid >> 6;
    int l15 = lane & 15, l4 = lane >> 4;
    int base = blockIdx.x * MT;
    int wrow = wave * 32;

    float sc1v[4], sh1v[4], sc2v[4], sh2v[4];
    #pragma unroll
    for (int ct = 0; ct < 4; ++ct) {
        int c = ct * 16 + l15;
        float s1 = g1[c] * rsqrtf(v1[c] + BN_EPS);
        sc1v[ct] = s1; sh1v[ct] = (lb1[c] - m1[c]) * s1 + bb1[c];
        float s2 = g2[c] * rsqrtf(v2[c] + BN_EPS);
        sc2v[ct] = s2; sh2v[ct] = (lb2[c] - m2[c]) * s2 + bb2[c];
    }

    // stage agg tile (bf16, padded rows)
    for (int i = tid; i < 128 * 8; i += 256) {
        int r = i >> 3, q = i & 7;
        int gr = base + r;
        uint4 u = (gr < NN) ? ((const uint4*)(agg + (size_t)gr * HH))[q] : make_uint4(0, 0, 0, 0);
        *(uint4*)&sHi[r * SAB + q * 8] = u;
    }
    __syncthreads();

    const bf16x8* fwv = (const bf16x8*)fragW + ((size_t)layer * 32) * 64;

    // ---- GEMM1
    bf16x8 a0[2][2];
    #pragma unroll
    for (int rt = 0; rt < 2; ++rt)
        #pragma unroll
        for (int kh = 0; kh < 2; ++kh)
            a0[rt][kh] = *(const bf16x8*)&sHi[(wrow + rt * 16 + l15) * SAB + kh * 32 + l4 * 8];

    f32x4 acc[2][4];
    #pragma unroll
    for (int rt = 0; rt < 2; ++rt)
        #pragma unroll
        for (int ct = 0; ct < 4; ++ct) {
            f32x4 c = {0.f, 0.f, 0.f, 0.f};
            #pragma unroll
            for (int kh = 0; kh < 2; ++kh) {
                c = __builtin_amdgcn_mfma_f32_16x16x32_bf16(a0[rt][kh], fwv[((0 * 4 + ct) * 2 + kh) * 64 + lane], c, 0, 0, 0); // W1hi
                c = __builtin_amdgcn_mfma_f32_16x16x32_bf16(a0[rt][kh], fwv[((1 * 4 + ct) * 2 + kh) * 64 + lane], c, 0, 0, 0); // W1lo
            }
            acc[rt][ct] = c;
        }
    __syncthreads();   // all waves done reading sHi

    // z1 = relu(bn1(acc)) split hi/lo -> sHi/sLo (A-layout, row-major shorts)
    #pragma unroll
    for (int rt = 0; rt < 2; ++rt)
        #pragma unroll
        for (int ct = 0; ct < 4; ++ct)
            #pragma unroll
            for (int rg = 0; rg < 4; ++rg) {
                int r = wrow + rt * 16 + l4 * 4 + rg;
                float z = fmaxf(fmaf(acc[rt][ct][rg], sc1v[ct], sh1v[ct]), 0.f);
                unsigned short hi = f2bf(z);
                sHi[r * SAB + ct * 16 + l15] = hi;
                sLo[r * SAB + ct * 16 + l15] = f2bf(z - bf2f(hi));
            }
    __syncthreads();

    // ---- GEMM2
    bf16x8 ah[2][2], al[2][2];
    #pragma unroll
    for (int rt = 0; rt < 2; ++rt)
        #pragma unroll
        for (int kh = 0; kh < 2; ++kh) {
            int off = (wrow + rt * 16 + l15) * SAB + kh * 32 + l4 * 8;
            ah[rt][kh] = *(const bf16x8*)&sHi[off];
            al[rt][kh] = *(const bf16x8*)&sLo[off];
        }
    #pragma unroll
    for (int rt = 0; rt < 2; ++rt)
        #pragma unroll
        for (int ct = 0; ct < 4; ++ct) {
            f32x4 c = {0.f, 0.f, 0.f, 0.f};
            #pragma unroll
            for (int kh = 0; kh < 2; ++kh) {
                bf16x8 bh = fwv[((2 * 4 + ct) * 2 + kh) * 64 + lane];   // W2hi
                bf16x8 bl = fwv[((3 * 4 + ct) * 2 + kh) * 64 + lane];   // W2lo
                c = __builtin_amdgcn_mfma_f32_16x16x32_bf16(ah[rt][kh], bh, c, 0, 0, 0);
                c = __builtin_amdgcn_mfma_f32_16x16x32_bf16(al[rt][kh], bh, c, 0, 0, 0);
                c = __builtin_amdgcn_mfma_f32_16x16x32_bf16(ah[rt][kh], bl, c, 0, 0, 0);
            }
            #pragma unroll
            for (int rg = 0; rg < 4; ++rg) {
                int r = wrow + rt * 16 + l4 * 4 + rg;
                float z = fmaxf(fmaf(c[rg], sc2v[ct], sh2v[ct]), 0.f);
                sOut[r * SOF + ct * 16 + l15] = z;
            }
        }
    __syncthreads();

    // h_out copy-out in split layout [2][NN][32]
    for (int i = tid; i < 128 * 8; i += 256) {
        int r = i >> 3, q = i & 7;
        int gr = base + r;
        if (gr < NN) {
            const float* sp = &sOut[r * SOF + q * 8];
            uint4 o;
            o.x = (unsigned int)f2bf(sp[0]) | ((unsigned int)f2bf(sp[1]) << 16);
            o.y = (unsigned int)f2bf(sp[2]) | ((unsigned int)f2bf(sp[3]) << 16);
            o.z = (unsigned int)f2bf(sp[4]) | ((unsigned int)f2bf(sp[5]) << 16);
            o.w = (unsigned int)f2bf(sp[6]) | ((unsigned int)f2bf(sp[7]) << 16);
            int half = q >> 2, qq = q & 3;
            ((uint4*)h_out)[((size_t)half * NN + gr) * 4 + qq] = o;
        }
    }

    // fused pooling over this tile's graph segments (batch sorted)
    int thi = base + MT; if (thi > NN) thi = NN;
    int gfirst = batch[base];
    int glast  = batch[thi - 1];
    int c = tid & 63;
    int q = tid >> 6;
    for (int g = gfirst; g <= glast; ++g) {
        int lo = base, hb = thi;
        while (lo < hb) { int mid = (lo + hb) >> 1; if (batch[mid] < g) lo = mid + 1; else hb = mid; }
        int lo_g = lo;
        hb = thi;
        while (lo < hb) { int mid = (lo + hb) >> 1; if (batch[mid] < g + 1) lo = mid + 1; else hb = mid; }
        int hi_g = lo;
        float a = 0.f;
        for (int r = lo_g + q; r < hi_g; r += 4) a += sOut[(r - base) * SOF + c];
        red[tid] = a;
        __syncthreads();
        if (tid < 64)
            atomicAdd(&pooled[(size_t)g * (LL * HH) + layer * HH + c],
                      red[c] + red[64 + c] + red[128 + c] + red[192 + c]);
        __syncthreads();
    }
}

// ---------------------------------------------------------------------------
// Final MLP: relu(pooled @ lin1 + b1) @ lin2 + b2. One block per graph.
// ---------------------------------------------------------------------------
__global__ __launch_bounds__(64) void k_mlp(const float* __restrict__ pooled,
                                            const float* __restrict__ w1, const float* __restrict__ b1,
                                            const float* __restrict__ w2, const float* __restrict__ b2,
                                            float* __restrict__ out)
{
    int g = blockIdx.x, c = threadIdx.x;
    __shared__ float hh[64];
    float acc = b1[c];
    const float* p = pooled + g * (LL * HH);
    #pragma unroll 8
    for (int k = 0; k < LL * HH; ++k) acc = fmaf(p[k], w1[k * HH + c], acc);
    hh[c] = fmaxf(acc, 0.f);
    __syncthreads();
    if (c < CC) {
        float o = b2[c];
        #pragma unroll
        for (int k = 0; k < HH; ++k) o = fmaf(hh[k], w2[k * CC + c], o);
        out[g * CC + c] = o;
    }
}

// ---------------------------------------------------------------------------
extern "C" void kernel_launch(void* const* d_in, const int* in_sizes, int n_in,
                              void* d_out, int out_size, void* d_ws, size_t ws_size,
                              hipStream_t stream) {
    const float* x    = (const float*)d_in[0];
    const int*   ei   = (const int*)d_in[1];
    const int*   bat  = (const int*)d_in[2];
    const float* cW1  = (const float*)d_in[3];
    const float* cb1  = (const float*)d_in[4];
    const float* g1   = (const float*)d_in[5];
    const float* bb1  = (const float*)d_in[6];
    const float* m1   = (const float*)d_in[7];
    const float* v1   = (const float*)d_in[8];
    const float* cW2  = (const float*)d_in[9];
    const float* cb2  = (const float*)d_in[10];
    const float* g2   = (const float*)d_in[11];
    const float* bb2  = (const float*)d_in[12];
    const float* m2   = (const float*)d_in[13];
    const float* v2   = (const float*)d_in[14];
    const float* l1W  = (const float*)d_in[15];
    const float* l1b  = (const float*)d_in[16];
    const float* l2W  = (const float*)d_in[17];
    const float* l2b  = (const float*)d_in[18];

    const int* srcp = ei;            // edge_index[0]
    const int* dstp = ei + NE;       // edge_index[1]

    char* ws = (char*)d_ws;
    size_t off = 0;
    auto alloc = [&](size_t bytes) -> char* {
        char* p = ws + off;
        off += (bytes + 255) & ~size_t(255);
        return p;
    };
    unsigned short* xb    = (unsigned short*)alloc((size_t)NN * HH * 2);
    unsigned short* hb0   = (unsigned short*)alloc((size_t)NN * HH * 2);
    unsigned short* hb1   = (unsigned short*)alloc((size_t)NN * HH * 2);
    unsigned short* aggb  = (unsigned short*)alloc((size_t)NN * HH * 2);
    unsigned short* fragW = (unsigned short*)alloc((size_t)LL * 32 * 512 * 2);
    // deg, cursor, pooled contiguous -> single memset covers all three
    int*   deg     = (int*)alloc((size_t)NN * sizeof(int));
    int*   cursor  = (int*)alloc((size_t)NN * sizeof(int));
    float* pooled  = (float*)alloc((size_t)GG * LL * HH * sizeof(float));
    size_t zspan   = (size_t)((char*)(pooled + (size_t)GG * LL * HH) - (char*)deg);
    int*   row_ptr = (int*)alloc((size_t)(NN + 1) * sizeof(int));
    int*   incl    = (int*)alloc((size_t)NN * sizeof(int));
    int*   colx    = (int*)alloc((size_t)NE * sizeof(int));
    int*   bsum    = (int*)alloc(256 * sizeof(int));

    (void)hipMemsetAsync(deg, 0, zspan, stream);

    // CSR build (XCD-partitioned) + x cast (split layout) + weight frag prep
    k_hist8<<<8 * NCHUNK, 256, 0, stream>>>(dstp, deg);
    k_prep<<<CASTB + 128, 256, 0, stream>>>(x, xb, cW1, cW2, fragW);
    k_scan1<<<SCB, 256, 0, stream>>>(deg, incl, bsum);
    k_scan3f<<<SCB, 256, 0, stream>>>(deg, incl, bsum, row_ptr);
    k_scatter8<<<8 * NCHUNK, 256, 0, stream>>>(srcp, dstp, row_ptr, cursor, colx);

    const unsigned short* hin = xb;
    unsigned short* bufs[2] = { hb0, hb1 };
    const int MLP_BLK = (NN + MT - 1) / MT;    // 391
    for (int l = 0; l < LL; ++l) {
        unsigned short* hout = bufs[l & 1];
        k_agg2<<<2 * AGGB2, 256, 0, stream>>>(hin, aggb, row_ptr, colx);
        k_mlp2<<<MLP_BLK, 256, 0, stream>>>(aggb, hout, bat, pooled, l, fragW,
            cb1 + l * HH, g1 + l * HH, bb1 + l * HH, m1 + l * HH, v1 + l * HH,
            cb2 + l * HH, g2 + l * HH, bb2 + l * HH, m2 + l * HH, v2 + l * HH);
        hin = hout;
    }

    k_mlp<<<GG, 64, 0, stream>>>(pooled, l1W, l1b, l2W, l2b, (float*)d_out);
}